// Round 1
// baseline (4080.141 us; speedup 1.0000x reference)
//
#include <hip/hip_runtime.h>

#define BATCH 4
#define NPTS  16384
#define CH    128
#define KNN   16
#define TILE  2048   // candidate tile staged in LDS (float4 -> 32KB)

// ---------------- workspace layout (bytes) ----------------
// xt   : [B][N][CH] float   off 0          33,554,432
// h_t  : [B][N][CH] float   off 33554432   33,554,432
// idx  : [B][N][16] int     off 67108864    4,194,304
// part : [256][4096] float  off 71303168    4,194,304
// stats: [256] float        off 75497472    1,024
#define XT_OFF    0
#define HT_OFF    33554432
#define IDX_OFF   67108864
#define PART_OFF  71303168
#define STATS_OFF 75497472

// ---------------------------------------------------------------------------
// 1) transpose x [B,CH,N] -> xt [B,N,CH]
__global__ __launch_bounds__(256) void transpose_kernel(const float* __restrict__ x,
                                                        float* __restrict__ xt) {
    __shared__ float t[32][33];
    const int b  = blockIdx.z;
    const int c0 = blockIdx.y * 32;
    const int n0 = blockIdx.x * 32;
    const int tx = threadIdx.x, ty = threadIdx.y;   // block (32,8)
#pragma unroll
    for (int i = 0; i < 4; ++i)
        t[ty + 8 * i][tx] = x[((size_t)b * CH + c0 + ty + 8 * i) * NPTS + n0 + tx];
    __syncthreads();
#pragma unroll
    for (int i = 0; i < 4; ++i)
        xt[((size_t)b * NPTS + n0 + ty + 8 * i) * CH + c0 + tx] = t[tx][ty + 8 * i];
}

// ---------------------------------------------------------------------------
// 2) exact KNN: one query per thread, insertion-sorted top-16 in registers.
//    Distances computed with non-fused rn ops in numpy association order so
//    the ordering is bit-identical to the reference.
__device__ __forceinline__ void insert16(float (&dq)[KNN], int (&iq)[KNN], float d, int gi) {
    float cd = d; int ci = gi;
#pragma unroll
    for (int s = KNN - 1; s >= 1; --s) {
        if (cd < dq[s - 1]) {
            dq[s] = dq[s - 1]; iq[s] = iq[s - 1];
            if (s == 1) { dq[0] = cd; iq[0] = ci; }
        } else {
            dq[s] = cd; iq[s] = ci;
            break;
        }
    }
}

__global__ __launch_bounds__(256) void knn_kernel(const float* __restrict__ xyz,
                                                  int* __restrict__ idx_out) {
    __shared__ float4 sP[TILE];
    const int b = blockIdx.y;
    const int q = blockIdx.x * 256 + threadIdx.x;
    const float* xb = xyz + (size_t)b * NPTS * 3;

    const float qx = xb[q * 3 + 0];
    const float qy = xb[q * 3 + 1];
    const float qz = xb[q * 3 + 2];

    float dq[KNN]; int iq[KNN];
#pragma unroll
    for (int s = 0; s < KNN; ++s) { dq[s] = 3.0e38f; iq[s] = 0; }
    float worst = 3.0e38f;

    for (int t0 = 0; t0 < NPTS; t0 += TILE) {
        __syncthreads();
#pragma unroll
        for (int i = 0; i < TILE / 256; ++i) {
            const int j = i * 256 + threadIdx.x;
            const float* p = xb + (size_t)(t0 + j) * 3;
            sP[j] = make_float4(p[0], p[1], p[2], 0.0f);
        }
        __syncthreads();

        for (int j = 0; j < TILE; j += 4) {
            const float4 p0 = sP[j + 0];
            const float4 p1 = sP[j + 1];
            const float4 p2 = sP[j + 2];
            const float4 p3 = sP[j + 3];
            float dx, dy, dz;
            dx = __fsub_rn(qx, p0.x); dy = __fsub_rn(qy, p0.y); dz = __fsub_rn(qz, p0.z);
            const float d0 = __fadd_rn(__fadd_rn(__fmul_rn(dx, dx), __fmul_rn(dy, dy)), __fmul_rn(dz, dz));
            dx = __fsub_rn(qx, p1.x); dy = __fsub_rn(qy, p1.y); dz = __fsub_rn(qz, p1.z);
            const float d1 = __fadd_rn(__fadd_rn(__fmul_rn(dx, dx), __fmul_rn(dy, dy)), __fmul_rn(dz, dz));
            dx = __fsub_rn(qx, p2.x); dy = __fsub_rn(qy, p2.y); dz = __fsub_rn(qz, p2.z);
            const float d2 = __fadd_rn(__fadd_rn(__fmul_rn(dx, dx), __fmul_rn(dy, dy)), __fmul_rn(dz, dz));
            dx = __fsub_rn(qx, p3.x); dy = __fsub_rn(qy, p3.y); dz = __fsub_rn(qz, p3.z);
            const float d3 = __fadd_rn(__fadd_rn(__fmul_rn(dx, dx), __fmul_rn(dy, dy)), __fmul_rn(dz, dz));

            if (fminf(fminf(d0, d1), fminf(d2, d3)) < worst) {
                if (d0 < worst) { insert16(dq, iq, d0, t0 + j + 0); worst = dq[KNN - 1]; }
                if (d1 < worst) { insert16(dq, iq, d1, t0 + j + 1); worst = dq[KNN - 1]; }
                if (d2 < worst) { insert16(dq, iq, d2, t0 + j + 2); worst = dq[KNN - 1]; }
                if (d3 < worst) { insert16(dq, iq, d3, t0 + j + 3); worst = dq[KNN - 1]; }
            }
        }
    }

    int* op = idx_out + ((size_t)b * NPTS + q) * KNN;
#pragma unroll
    for (int s = 0; s < KNN; ++s) op[s] = iq[s];
}

// ---------------------------------------------------------------------------
// 3) gather + Laplacian dx + 1x1 conv + relu + BN partial sums.
//    One block = 128 threads (thread == channel), 16 points per block.
//    W row of this thread's output channel lives in registers (32 x float4).
__global__ __launch_bounds__(128) void conv_kernel(const float* __restrict__ xt,
                                                   const int* __restrict__ idx,
                                                   const float* __restrict__ W,
                                                   const float* __restrict__ bias,
                                                   float* __restrict__ h_t,
                                                   float* __restrict__ partials) {
    __shared__ __align__(16) float dxbuf[CH];
    const int o   = threadIdx.x;                 // channel (both for gather and output)
    const int blk = blockIdx.x;                  // 0..4095
    const int b   = blk / (NPTS / 16);
    const int n0  = (blk % (NPTS / 16)) * 16;

    float4 w4[CH / 4];
    const float4* wrow = (const float4*)(W + (size_t)o * CH);
#pragma unroll
    for (int i = 0; i < CH / 4; ++i) w4[i] = wrow[i];
    const float bo = bias[o];

    const float* xb = xt + (size_t)b * NPTS * CH;
    float sS = 0.0f, sQ = 0.0f;

    for (int r = 0; r < 16; ++r) {
        const int n = n0 + r;
        const int* ip = idx + ((size_t)b * NPTS + n) * KNN;
        int jj[KNN];
#pragma unroll
        for (int k = 0; k < KNN; ++k) jj[k] = ip[k];
        float va[KNN];
#pragma unroll
        for (int k = 0; k < KNN; ++k) va[k] = xb[(size_t)jj[k] * CH + o];
        const float ctr = xb[(size_t)n * CH + o];
        float acc = 0.0f;
#pragma unroll
        for (int k = 0; k < KNN; ++k) acc += va[k];
        acc -= ctr;

        dxbuf[o] = acc;
        __syncthreads();

        float h = bo;
        const float4* d4 = (const float4*)dxbuf;
#pragma unroll
        for (int cc = 0; cc < CH / 4; ++cc) {
            const float4 a = d4[cc];
            const float4 w = w4[cc];
            h = fmaf(w.x, a.x, h);
            h = fmaf(w.y, a.y, h);
            h = fmaf(w.z, a.z, h);
            h = fmaf(w.w, a.w, h);
        }
        h = fmaxf(h, 0.0f);
        h_t[((size_t)b * NPTS + n) * CH + o] = h;
        sS += h;
        sQ += h * h;
        __syncthreads();
    }

    partials[(size_t)o * 4096 + blk]        = sS;
    partials[(size_t)(CH + o) * 4096 + blk] = sQ;
}

// ---------------------------------------------------------------------------
// 4) reduce partials -> mean / rstd per channel (deterministic)
__global__ __launch_bounds__(256) void bnred_kernel(const float* __restrict__ partials,
                                                    float* __restrict__ stats) {
    const int ch = blockIdx.x;   // 0..127
    const float* pS = partials + (size_t)ch * 4096;
    const float* pQ = partials + (size_t)(CH + ch) * 4096;
    float s = 0.0f, q = 0.0f;
    for (int i = threadIdx.x; i < 4096; i += 256) { s += pS[i]; q += pQ[i]; }
#pragma unroll
    for (int off = 32; off > 0; off >>= 1) {
        s += __shfl_down(s, off);
        q += __shfl_down(q, off);
    }
    __shared__ float wsum[4][2];
    const int wid = threadIdx.x >> 6;
    if ((threadIdx.x & 63) == 0) { wsum[wid][0] = s; wsum[wid][1] = q; }
    __syncthreads();
    if (threadIdx.x == 0) {
        const float S = wsum[0][0] + wsum[1][0] + wsum[2][0] + wsum[3][0];
        const float Q = wsum[0][1] + wsum[1][1] + wsum[2][1] + wsum[3][1];
        const float inv  = 1.0f / (float)(BATCH * NPTS);
        const float mean = S * inv;
        const float var  = Q * inv - mean * mean;
        stats[ch]      = mean;
        stats[CH + ch] = rsqrtf(var + 1e-5f);
    }
}

// ---------------------------------------------------------------------------
// 5) out[b,c,n] = x + gamma*(h - mean)*rstd + beta   (h stored [B,N,CH])
__global__ __launch_bounds__(256) void final_kernel(const float* __restrict__ x,
                                                    const float* __restrict__ h_t,
                                                    const float* __restrict__ stats,
                                                    const float* __restrict__ gamma,
                                                    const float* __restrict__ beta,
                                                    float* __restrict__ out) {
    __shared__ float t[32][33];
    const int b  = blockIdx.z;
    const int o0 = blockIdx.y * 32;
    const int n0 = blockIdx.x * 32;
    const int tx = threadIdx.x, ty = threadIdx.y;   // block (32,8)
#pragma unroll
    for (int i = 0; i < 4; ++i)
        t[ty + 8 * i][tx] = h_t[((size_t)b * NPTS + n0 + ty + 8 * i) * CH + o0 + tx];
    __syncthreads();
#pragma unroll
    for (int i = 0; i < 4; ++i) {
        const int o = o0 + ty + 8 * i;
        const float mean = stats[o];
        const float rstd = stats[CH + o];
        const float g = gamma[o], be = beta[o];
        const size_t off = ((size_t)b * CH + o) * NPTS + n0 + tx;
        out[off] = x[off] + g * ((t[tx][ty + 8 * i] - mean) * rstd) + be;
    }
}

// ---------------------------------------------------------------------------
extern "C" void kernel_launch(void* const* d_in, const int* in_sizes, int n_in,
                              void* d_out, int out_size, void* d_ws, size_t ws_size,
                              hipStream_t stream) {
    const float* xyz    = (const float*)d_in[0];
    const float* x      = (const float*)d_in[1];
    const float* conv_w = (const float*)d_in[2];
    const float* conv_b = (const float*)d_in[3];
    const float* gamma  = (const float*)d_in[4];
    const float* beta   = (const float*)d_in[5];
    float* out = (float*)d_out;

    char* ws = (char*)d_ws;
    float* xt    = (float*)(ws + XT_OFF);
    float* h_t   = (float*)(ws + HT_OFF);
    int*   idx   = (int*)  (ws + IDX_OFF);
    float* part  = (float*)(ws + PART_OFF);
    float* stats = (float*)(ws + STATS_OFF);

    // 1) transpose features
    transpose_kernel<<<dim3(NPTS / 32, CH / 32, BATCH), dim3(32, 8), 0, stream>>>(x, xt);
    // 2) knn
    knn_kernel<<<dim3(NPTS / 256, BATCH), dim3(256), 0, stream>>>(xyz, idx);
    // 3) gather + conv + relu + partial BN sums
    conv_kernel<<<dim3(BATCH * NPTS / 16), dim3(128), 0, stream>>>(xt, idx, conv_w, conv_b, h_t, part);
    // 4) BN stats
    bnred_kernel<<<dim3(CH), dim3(256), 0, stream>>>(part, stats);
    // 5) residual + BN apply (transpose back)
    final_kernel<<<dim3(NPTS / 32, CH / 32, BATCH), dim3(32, 8), 0, stream>>>(x, h_t, stats, gamma, beta, out);
}